// Round 8
// baseline (377.605 us; speedup 1.0000x reference)
//
#include <hip/hip_runtime.h>

// ---------------------------------------------------------------------------
// MultiheadCosformerAttention: B=4, L=4096, E=1024, H=16, hd=64
// Round 12: 32x32 MFMA reverted (9.4e6 bank conflicts, -10us). Back to the
//           round-10 16x16 core (341.1 us best). New: x fp32->bf16 conversion
//           fused into gemm_qkv's A-staging (reg-stage: 2x float4 load ->
//           v_cvt_pk_bf16_f32 -> swizzled ds_write_b128, 2-tile pipelined),
//           eliminating the 22us cvt pass over x and xb's 64MB roundtrip.
//           cvt kernel now converts weights only (~4us).
// ---------------------------------------------------------------------------

typedef unsigned short u16;
typedef unsigned int u32;
typedef __attribute__((ext_vector_type(8))) __bf16 bf16x8;
typedef __attribute__((ext_vector_type(4))) float f32x4;

#define PI_HALF 1.57079632679489662f
#define EPS_Z 1e-4f

__device__ __forceinline__ u16 f32_to_bf16(float f) {
    union { float f; unsigned int u; } x; x.f = f;
    unsigned int lsb = (x.u >> 16) & 1u;
    x.u += 0x7fffu + lsb;                 // round-to-nearest-even
    return (u16)(x.u >> 16);
}
__device__ __forceinline__ u32 cvt_pk2(float a, float b) {
    u32 r;
    asm("v_cvt_pk_bf16_f32 %0, %1, %2" : "=v"(r) : "v"(a), "v"(b));
    return r;   // lo = bf16(a), hi = bf16(b), RNE
}

typedef __attribute__((address_space(1))) void amdgpu_global_t;
typedef __attribute__((address_space(3))) void amdgpu_lds_t;
__device__ __forceinline__ void async_load16(const u16* g, u16* l) {
    __builtin_amdgcn_global_load_lds((amdgpu_global_t*)g, (amdgpu_lds_t*)l, 16, 0, 0);
}

// ---------------------------------------------------------------------------
// fp32 -> bf16 weight conversion (weights only; x handled inside gemm_qkv).
// ---------------------------------------------------------------------------
__global__ __launch_bounds__(256) void cvt_w4(const float* __restrict__ w0,
                                              const float* __restrict__ w1,
                                              const float* __restrict__ w2,
                                              const float* __restrict__ w3,
                                              u16* __restrict__ wcat) {
    const float* src = (blockIdx.y == 0) ? w0 : (blockIdx.y == 1) ? w1
                     : (blockIdx.y == 2) ? w2 : w3;
    u16* dst = wcat + (size_t)blockIdx.y * 1048576;
    int i = blockIdx.x * 256 + threadIdx.x;
    float4 f = ((const float4*)src)[i];
    ushort4 o;
    o.x = f32_to_bf16(f.x); o.y = f32_to_bf16(f.y);
    o.z = f32_to_bf16(f.z); o.w = f32_to_bf16(f.w);
    ((ushort4*)dst)[i] = o;
}

// ---------------------------------------------------------------------------
// 256x256 / BK=64 / 8-wave GEMM core, bf16 A+B via global_load_lds.
// 2 barriers per K-tile, counted vmcnt(8). (round-10 version, 341.1us best)
// ---------------------------------------------------------------------------
__device__ __forceinline__ void gemm256_core(const u16* __restrict__ Abase,
                                             const u16* __restrict__ Bbase,
                                             u16* As, u16* Bs,
                                             f32x4 (&acc)[8][4]) {
    const int tid  = threadIdx.x;
    const int wave = tid >> 6;
    const int lane = tid & 63;
    const int quad = lane >> 4;
    const int l15  = lane & 15;
    const int wr   = wave >> 2;
    const int wc   = wave & 3;
    const int srow = tid >> 3;
    const int scg  = (tid & 7) ^ (srow & 7);

    const u16* Ag = Abase + ((long)srow << 10) + scg * 8;
    const u16* Bg = Bbase + ((long)srow << 10) + scg * 8;

    auto stage = [&](const u16* g, u16* lb, int hs, int t) {
        async_load16(g + ((long)hs << 16) + (t << 6), lb + hs * 4096);
    };
    auto rdA = [&](const u16* buf, int mf, int kk) -> bf16x8 {
        const int R = wr * 128 + mf * 16 + l15;
        return *(const bf16x8*)(buf + R * 64 + ((kk * 32 + quad * 8) ^ ((R & 7) * 8)));
    };
    auto rdB = [&](const u16* buf, int nf, int kk) -> bf16x8 {
        const int R = wc * 64 + nf * 16 + l15;
        return *(const bf16x8*)(buf + R * 64 + ((kk * 32 + quad * 8) ^ ((R & 7) * 8)));
    };

    bf16x8 a[4][2], b[4][2];
    auto mfma8 = [&](int i0, int j0) {
        __builtin_amdgcn_s_setprio(1);
#pragma unroll
        for (int i = 0; i < 4; ++i)
#pragma unroll
            for (int j = 0; j < 2; ++j)
#pragma unroll
                for (int kk = 0; kk < 2; ++kk)
                    acc[i0 + i][j0 + j] = __builtin_amdgcn_mfma_f32_16x16x32_bf16(
                        a[i][kk], b[j0 + j][kk], acc[i0 + i][j0 + j], 0, 0, 0);
        __builtin_amdgcn_s_setprio(0);
    };

#pragma unroll
    for (int hs = 0; hs < 4; ++hs) stage(Ag, As + wave * 512, hs, 0);
#pragma unroll
    for (int hs = 0; hs < 4; ++hs) stage(Bg, Bs + wave * 512, hs, 0);
#pragma unroll
    for (int hs = 0; hs < 4; ++hs) stage(Ag, As + 16384 + wave * 512, hs, 1);
#pragma unroll
    for (int hs = 0; hs < 4; ++hs) stage(Bg, Bs + 16384 + wave * 512, hs, 1);
    asm volatile("s_waitcnt vmcnt(8)" ::: "memory");
    __builtin_amdgcn_s_barrier();

#pragma unroll 1
    for (int t = 0; t < 16; ++t) {
        const int cur = t & 1;
        const u16* Ab = As + cur * 16384;
        const u16* Bb = Bs + cur * 16384;
        u16* lA = As + cur * 16384 + wave * 512;
        u16* lB = Bs + cur * 16384 + wave * 512;
        const bool pf = (t < 14);

#pragma unroll
        for (int i = 0; i < 4; ++i) { a[i][0] = rdA(Ab, i, 0); a[i][1] = rdA(Ab, i, 1); }
#pragma unroll
        for (int j = 0; j < 2; ++j) { b[j][0] = rdB(Bb, j, 0); b[j][1] = rdB(Bb, j, 1); }
        mfma8(0, 0);
#pragma unroll
        for (int j = 2; j < 4; ++j) { b[j][0] = rdB(Bb, j, 0); b[j][1] = rdB(Bb, j, 1); }
        mfma8(0, 2);
#pragma unroll
        for (int i = 0; i < 4; ++i) { a[i][0] = rdA(Ab, i + 4, 0); a[i][1] = rdA(Ab, i + 4, 1); }
        mfma8(4, 0);

        __builtin_amdgcn_s_barrier();
        asm volatile("" ::: "memory");
        if (pf) {
#pragma unroll
            for (int hs = 0; hs < 4; ++hs) stage(Bg, lB, hs, t + 2);
#pragma unroll
            for (int hs = 0; hs < 4; ++hs) stage(Ag, lA, hs, t + 2);
        }
        mfma8(4, 2);
        if (pf) {
            asm volatile("s_waitcnt vmcnt(8)" ::: "memory");
        } else {
            asm volatile("s_waitcnt vmcnt(0)" ::: "memory");
        }
        __builtin_amdgcn_s_barrier();
        asm volatile("" ::: "memory");
    }
}

// ---------------------------------------------------------------------------
// Variant: A read as fp32 (x directly), converted in-register during staging.
// A: reg-stage (2x float4 -> 4x v_cvt_pk_bf16_f32 -> swizzled ds_write_b128),
//    pipelined 2 tiles deep (issue A(t+3) pre-barrier2, write A(t+2) post-C4).
// B: global_load_lds as before. Same 2-barrier schedule.
// ---------------------------------------------------------------------------
__device__ __forceinline__ void gemm256_f32a(const float* __restrict__ Af,
                                             const u16* __restrict__ Bbase,
                                             u16* As, u16* Bs,
                                             f32x4 (&acc)[8][4]) {
    const int tid  = threadIdx.x;
    const int wave = tid >> 6;
    const int lane = tid & 63;
    const int quad = lane >> 4;
    const int l15  = lane & 15;
    const int wr   = wave >> 2;
    const int wc   = wave & 3;
    const int srow = tid >> 3;                 // 0..63
    const int c8   = (tid & 7) * 8;            // linear col (elem idx)
    const int scg  = (tid & 7) ^ (srow & 7);   // pre-swizzled src group (B)
    const int wcol = c8 ^ ((srow & 7) * 8);    // swizzled LDS col (A write)

    const float* Ax = Af + ((long)srow << 10) + c8;
    const u16*   Bg = Bbase + ((long)srow << 10) + scg * 8;

    auto stageB = [&](u16* lb, int hs, int t) {
        async_load16(Bg + ((long)hs << 16) + (t << 6), lb + hs * 4096);
    };
    auto rdA = [&](const u16* buf, int mf, int kk) -> bf16x8 {
        const int R = wr * 128 + mf * 16 + l15;
        return *(const bf16x8*)(buf + R * 64 + ((kk * 32 + quad * 8) ^ ((R & 7) * 8)));
    };
    auto rdB = [&](const u16* buf, int nf, int kk) -> bf16x8 {
        const int R = wc * 64 + nf * 16 + l15;
        return *(const bf16x8*)(buf + R * 64 + ((kk * 32 + quad * 8) ^ ((R & 7) * 8)));
    };

    float4 ar[8];                              // one K-tile of A fp32 (32 f)
    auto loadA = [&](int t) {
#pragma unroll
        for (int hs = 0; hs < 4; ++hs) {
            const float* p = Ax + ((long)hs << 16) + (t << 6);
            ar[hs * 2]     = *(const float4*)p;
            ar[hs * 2 + 1] = *(const float4*)(p + 4);
        }
    };
    auto writeA = [&](u16* base) {             // base = As + cur*16384
#pragma unroll
        for (int hs = 0; hs < 4; ++hs) {
            uint4 pk;
            pk.x = cvt_pk2(ar[hs * 2].x,     ar[hs * 2].y);
            pk.y = cvt_pk2(ar[hs * 2].z,     ar[hs * 2].w);
            pk.z = cvt_pk2(ar[hs * 2 + 1].x, ar[hs * 2 + 1].y);
            pk.w = cvt_pk2(ar[hs * 2 + 1].z, ar[hs * 2 + 1].w);
            *(uint4*)(base + hs * 4096 + srow * 64 + wcol) = pk;
        }
    };

    bf16x8 a[4][2], b[4][2];
    auto mfma8 = [&](int i0, int j0) {
        __builtin_amdgcn_s_setprio(1);
#pragma unroll
        for (int i = 0; i < 4; ++i)
#pragma unroll
            for (int j = 0; j < 2; ++j)
#pragma unroll
                for (int kk = 0; kk < 2; ++kk)
                    acc[i0 + i][j0 + j] = __builtin_amdgcn_mfma_f32_16x16x32_bf16(
                        a[i][kk], b[j0 + j][kk], acc[i0 + i][j0 + j], 0, 0, 0);
        __builtin_amdgcn_s_setprio(0);
    };

    // prologue: A0,A1 via regs; B0,B1 via gload_lds; A2 left in flight
    loadA(0);
    writeA(As);                     // compiler waits A0 regs
    loadA(1);
    writeA(As + 16384);
#pragma unroll
    for (int hs = 0; hs < 4; ++hs) stageB(Bs + wave * 512, hs, 0);
#pragma unroll
    for (int hs = 0; hs < 4; ++hs) stageB(Bs + 16384 + wave * 512, hs, 1);
    loadA(2);
    asm volatile("s_waitcnt vmcnt(8)" ::: "memory");   // B0 resident (A2 stays)
    asm volatile("s_waitcnt lgkmcnt(0)" ::: "memory"); // A writes durable
    __builtin_amdgcn_s_barrier();

#pragma unroll 1
    for (int t = 0; t < 16; ++t) {
        const int cur = t & 1;
        const u16* Ab = As + cur * 16384;
        const u16* Bb = Bs + cur * 16384;
        u16* lB = Bs + cur * 16384 + wave * 512;
        const bool pf = (t < 14);    // stage B(t+2)
        const bool pw = (t <= 13);   // write A(t+2) from regs
        const bool pi = (t <= 12);   // issue A(t+3)

#pragma unroll
        for (int i = 0; i < 4; ++i) { a[i][0] = rdA(Ab, i, 0); a[i][1] = rdA(Ab, i, 1); }
#pragma unroll
        for (int j = 0; j < 2; ++j) { b[j][0] = rdB(Bb, j, 0); b[j][1] = rdB(Bb, j, 1); }
        mfma8(0, 0);
#pragma unroll
        for (int j = 2; j < 4; ++j) { b[j][0] = rdB(Bb, j, 0); b[j][1] = rdB(Bb, j, 1); }
        mfma8(0, 2);
#pragma unroll
        for (int i = 0; i < 4; ++i) { a[i][0] = rdA(Ab, i + 4, 0); a[i][1] = rdA(Ab, i + 4, 1); }
        mfma8(4, 0);

        __builtin_amdgcn_s_barrier();        // all waves done reading cur
        asm volatile("" ::: "memory");
        if (pf) {
#pragma unroll
            for (int hs = 0; hs < 4; ++hs) stageB(lB, hs, t + 2);
        }
        mfma8(4, 2);                         // covers B issue + A-reg latency
        if (pw) writeA(As + cur * 16384);    // auto vmcnt wait on ar
        if (pf) {
            asm volatile("s_waitcnt vmcnt(4)" ::: "memory");   // B(t+1) resident
        } else {
            asm volatile("s_waitcnt vmcnt(0)" ::: "memory");
        }
        asm volatile("s_waitcnt lgkmcnt(0)" ::: "memory");     // A writes durable
        if (pi) loadA(t + 3);                // in flight across barrier
        __builtin_amdgcn_s_barrier();
        asm volatile("" ::: "memory");
    }
}

// ---------------------------------------------------------------------------
// Fused QKV GEMM, A = x fp32. Wcat = [3072][1024]. Grid: 768 blocks of 512.
// ---------------------------------------------------------------------------
__global__ __launch_bounds__(512, 2) void gemm_qkv(const float* __restrict__ X,
                                                   const u16* __restrict__ Wcat,
                                                   const float* __restrict__ bq,
                                                   const float* __restrict__ bk,
                                                   const float* __restrict__ bv,
                                                   u16* __restrict__ qo,
                                                   u16* __restrict__ ko,
                                                   u16* __restrict__ vo) {
    __shared__ __align__(16) u16 As[32768];
    __shared__ __align__(16) u16 Bs[32768];
    const int bid = blockIdx.x;                    // 768 = 64 M x 12 N
    const int swz = (bid & 7) * 96 + (bid >> 3);   // XCD swizzle
    const int bx  = swz / 12;
    const int byy = swz - bx * 12;
    const long tileM = (long)bx * 256;

    f32x4 acc[8][4] = {};
    gemm256_f32a(X + (tileM << 10), Wcat + ((long)byy << 18), As, Bs, acc);

    const int tid  = (int)threadIdx.x;
    const int wave = tid >> 6;
    const int lane = tid & 63;
    const int quad = lane >> 4, l15 = lane & 15;
    const int wr = wave >> 2, wc = wave & 3;
    const int mat = byy >> 2;                      // 0:q 1:k 2:v
    const float* bias = (mat == 0) ? bq : (mat == 1) ? bk : bv;
    u16* outp = (mat == 0) ? qo : (mat == 1) ? ko : vo;
    const bool relu = (mat < 2);
    const int ncol0 = (byy & 3) * 256;

    const int rloc = tid >> 5;
    const int c8   = (tid & 31) * 8;
#pragma unroll 1
    for (int pass = 0; pass < 2; ++pass) {
        __syncthreads();
        if (wr == pass) {
#pragma unroll
            for (int i = 0; i < 8; ++i)
#pragma unroll
                for (int j = 0; j < 4; ++j) {
                    const int col = wc * 64 + j * 16 + l15;
                    const float bb = bias[ncol0 + col];
#pragma unroll
                    for (int r = 0; r < 4; ++r) {
                        const int row = i * 16 + quad * 4 + r;
                        float v = acc[i][j][r] + bb;
                        if (relu) v = fmaxf(v, 0.0f);
                        As[row * 256 + col] = f32_to_bf16(v);
                    }
                }
        }
        __syncthreads();
        const long gr0 = tileM + pass * 128;
#pragma unroll
        for (int it = 0; it < 8; ++it) {
            const int row = it * 16 + rloc;
            uint4 t4 = *(const uint4*)&As[row * 256 + c8];
            *(uint4*)&outp[(gr0 + row) * 1024 + ncol0 + c8] = t4;
        }
    }
}

// ---------------------------------------------------------------------------
// Output-projection GEMM (fp32 out). Grid: 256 blocks of 512.
// ---------------------------------------------------------------------------
__global__ __launch_bounds__(512, 2) void gemm_o(const u16* __restrict__ A,
                                                 const u16* __restrict__ Bw,
                                                 const float* __restrict__ bias,
                                                 float* __restrict__ Cout) {
    __shared__ __align__(16) u16 As[32768];
    __shared__ __align__(16) u16 Bs[32768];
    const int bid = blockIdx.x;
    const int swz = (bid & 7) * 32 + (bid >> 3);
    const long tileM = (long)(swz >> 2) * 256;
    const long tileN = (long)(swz & 3) * 256;

    f32x4 acc[8][4] = {};
    gemm256_core(A + (tileM << 10), Bw + (tileN << 10), As, Bs, acc);

    const int wave = (int)threadIdx.x >> 6;
    const int lane = (int)threadIdx.x & 63;
    const int quad = lane >> 4, l15 = lane & 15;
    const int wr = wave >> 2, wc = wave & 3;
#pragma unroll
    for (int j = 0; j < 4; ++j) {
        const long n = tileN + wc * 64 + j * 16 + l15;
        const float bb = bias[n];
#pragma unroll
        for (int i = 0; i < 8; ++i) {
            const long m0 = tileM + wr * 128 + i * 16 + quad * 4;
#pragma unroll
            for (int r = 0; r < 4; ++r)
                Cout[(m0 + r) * 1024 + n] = acc[i][j][r] + bb;
        }
    }
}

// ---------------------------------------------------------------------------
// Stage C (MFMA): per (chunk, head): part[d2=128][n=80] = k_^T @ [v | 1 | 0]
//   over K = 512 l's. 64-l K-tiles, register prefetch of next-kt loads.
// grid (8, 64), 256 threads = 4 waves.
// ---------------------------------------------------------------------------
__global__ __launch_bounds__(256) void kv_mfma(const u16* __restrict__ kmat,
                                               const u16* __restrict__ vmat,
                                               float* __restrict__ part) {
    __shared__ u16 Ak[64 * 72];
    __shared__ u16 Bv[64 * 72];
    const int tid = threadIdx.x;
    const int wave = tid >> 6, lane = tid & 63;
    const int quad = lane >> 4, l15 = lane & 15;
    const int head = blockIdx.y;
    const int b = head >> 4, h = head & 15;
    const int l0 = blockIdx.x * 512;
    const int sl = tid >> 3;
    const int sc8 = tid & 7;
    const int scol = sl ^ ((sc8 & 3) << 3);
    const int krow_base = (wave & 1) * 32;
    const bool use_cos = (wave >> 1) != 0;
    const int mbase = wave * 32;

    float sv[8], cv[8], s2[8], c2[8];
#pragma unroll
    for (int e = 0; e < 8; e++) {
        float ang = (PI_HALF / 4096.0f) * (float)(l0 + quad * 8 + e + 1);
        sv[e] = sinf(ang); cv[e] = cosf(ang);
        float ang2 = ang + (PI_HALF / 4096.0f) * 32.0f;
        s2[e] = sinf(ang2); c2[e] = cosf(ang2);
    }
    const float cD = 0.99969881869620422f;  // cos(pi/128)
    const float sD = 0.02454122852291229f;  // sin(pi/128)

    bf16x8 onesf;
#pragma unroll
    for (int e = 0; e < 8; e++)
        onesf[e] = (l15 == 0) ? (__bf16)1.0f : (__bf16)0.0f;

    f32x4 acc[2][5] = {};

    long row = ((long)b * 4096 + l0 + sl) * 1024 + h * 64 + sc8 * 8;
    uint4 kkA = *(const uint4*)(kmat + row);
    uint4 vvA = *(const uint4*)(vmat + row);
    uint4 kkB = *(const uint4*)(kmat + row + 32 * 1024);
    uint4 vvB = *(const uint4*)(vmat + row + 32 * 1024);

#pragma unroll 1
    for (int kt = 0; kt < 8; kt++) {
        uint4 kkA_n = {}, vvA_n = {}, kkB_n = {}, vvB_n = {};
        if (kt < 7) {
            row += 64 * 1024;
            kkA_n = *(const uint4*)(kmat + row);
            vvA_n = *(const uint4*)(vmat + row);
            kkB_n = *(const uint4*)(kmat + row + 32 * 1024);
            vvB_n = *(const uint4*)(vmat + row + 32 * 1024);
        }
        {
            const u16* kp = (const u16*)&kkA;
            const u16* vp = (const u16*)&vvA;
            const u16* kp2 = (const u16*)&kkB;
            const u16* vp2 = (const u16*)&vvB;
#pragma unroll
            for (int e = 0; e < 8; e++) {
                const int d = sc8 * 8 + e;
                Ak[d * 72 + scol]      = kp[e];
                Bv[d * 72 + scol]      = vp[e];
                Ak[d * 72 + scol + 32] = kp2[e];
                Bv[d * 72 + scol + 32] = vp2[e];
            }
        }
        __syncthreads();

        bf16x8 af[2][2];
#pragma unroll
        for (int i = 0; i < 2; i++) {
            const int d = krow_base + i * 16 + l15;
            const int q2 = (quad ^ ((d >> 3) & 3)) * 8;
#pragma unroll
            for (int kk = 0; kk < 2; kk++) {
                bf16x8 raw = *(const bf16x8*)&Ak[d * 72 + kk * 32 + q2];
                bf16x8 sc;
#pragma unroll
                for (int e = 0; e < 8; e++) {
                    const float s = use_cos ? (kk ? c2[e] : cv[e])
                                            : (kk ? s2[e] : sv[e]);
                    sc[e] = (__bf16)((float)raw[e] * s);
                }
                af[i][kk] = sc;
            }
        }
        bf16x8 bfr[5][2];
#pragma unroll
        for (int j = 0; j < 4; j++) {
            const int n = j * 16 + l15;
            const int q2 = (quad ^ ((n >> 3) & 3)) * 8;
            bfr[j][0] = *(const bf16x8*)&Bv[n * 72 + q2];
            bfr[j][1] = *(const bf16x8*)&Bv[n * 72 + 32 + q2];
        }
        bfr[4][0] = onesf; bfr[4][1] = onesf;
#pragma unroll
        for (int i = 0; i < 2; i++)
#pragma unroll
            for (int j = 0; j < 5; j++) {
                acc[i][j] = __builtin_amdgcn_mfma_f32_16x16x32_bf16(
                    af[i][0], bfr[j][0], acc[i][j], 0, 0, 0);
                acc[i][j] = __builtin_amdgcn_mfma_f32_16x16x32_bf16(
                    af[i][1], bfr[j][1], acc[i][j], 0, 0, 0);
            }

#pragma unroll
        for (int e = 0; e < 8; e++) {
            float ns = sv[e] * cD + cv[e] * sD;
            cv[e] = cv[e] * cD - sv[e] * sD;
            sv[e] = ns;
            ns = s2[e] * cD + c2[e] * sD;
            c2[e] = c2[e] * cD - s2[e] * sD;
            s2[e] = ns;
        }
        __syncthreads();
        kkA = kkA_n; vvA = vvA_n; kkB = kkB_n; vvB = vvB_n;
    }

    float* op = part + ((long)blockIdx.x * 64 + head) * 10240;
#pragma unroll
    for (int i = 0; i < 2; i++)
#pragma unroll
        for (int j = 0; j < 5; j++)
#pragma unroll
            for (int r = 0; r < 4; r++)
                op[(mbase + i * 16 + quad * 4 + r) * 80 + j * 16 + l15] = acc[i][j][r];
}

// ---------------------------------------------------------------------------
// Stage C2: sum 8 chunk-partials, transpose to Bt[head][n=80][d2=128] bf16.
// ---------------------------------------------------------------------------
__global__ __launch_bounds__(256) void kv_reduce_t(const float* __restrict__ part,
                                                   u16* __restrict__ Bt) {
    __shared__ float accs[32 * 81];
    const int head = blockIdx.y, d2t = blockIdx.x;
    const float* bp = part + (long)head * 10240 + d2t * 32 * 80;
    for (int idx = threadIdx.x; idx < 2560; idx += 256) {
        float s = 0.0f;
#pragma unroll
        for (int c = 0; c < 8; c++) s += bp[(long)c * 655360 + idx];
        const int d2 = idx / 80, n = idx - d2 * 80;
        accs[d2 * 81 + n] = s;
    }
    __syncthreads();
    for (int idx = threadIdx.x; idx < 2560; idx += 256) {
        const int n = idx >> 5, d2 = idx & 31;
        Bt[(long)head * 10240 + n * 128 + d2t * 32 + d2] = f32_to_bf16(accs[d2 * 81 + n]);
    }
}

// ---------------------------------------------------------------------------
// Stage D: per-head MFMA GEMM: attn[l, 0..79] = q_[l, 0..127] @ Bt^T
// 256 q-rows per block. grid (16, 64), 256 threads.
// ---------------------------------------------------------------------------
__global__ __launch_bounds__(256) void attn_mfma(const u16* __restrict__ qb,
                                                 const u16* __restrict__ Bt,
                                                 u16* __restrict__ merged) {
    __shared__ __align__(16) u16 As[128 * 72];
    __shared__ __align__(16) u16 Bs[80 * 136];
    const int tid = threadIdx.x;
    const int wave = tid >> 6, lane = tid & 63;
    const int quad = lane >> 4, l15 = lane & 15;
    const int head = blockIdx.y;
    const int b = head >> 4, h = head & 15;
    const int tm0 = blockIdx.x * 256;
    const long b4 = (long)b * 4096;
    const int wm = wave * 32;

    for (int c = tid; c < 1280; c += 256) {
        const int row = c >> 4, c16 = c & 15;
        uint4 t = *(const uint4*)(Bt + (long)head * 10240 + row * 128 + c16 * 8);
        *(uint4*)&Bs[row * 136 + c16 * 8] = t;
    }

#pragma unroll 1
    for (int half = 0; half < 2; ++half) {
        const int tm = tm0 + half * 128;
        __syncthreads();
        for (int c = tid; c < 1024; c += 256) {
            const int row = c >> 3, c8 = c & 7;
            uint4 t = *(const uint4*)(qb + (b4 + tm + row) * 1024 + h * 64 + c8 * 8);
            *(uint4*)&As[row * 72 + c8 * 8] = t;
        }
        float snl[2], csl[2];
#pragma unroll
        for (int i = 0; i < 2; i++) {
            const int l = tm + wm + i * 16 + l15;
            const float idx = PI_HALF * (float)(l + 1) * (1.0f / 4096.0f);
            snl[i] = sinf(idx); csl[i] = cosf(idx);
        }
        __syncthreads();

        f32x4 acc[2][5] = {};
#pragma unroll
        for (int kb = 0; kb < 4; kb++) {
            const int qc = (kb & 1) * 32 + quad * 8;
            bf16x8 af[2];
#pragma unroll
            for (int i = 0; i < 2; i++) {
                bf16x8 raw = *(const bf16x8*)&As[(wm + i * 16 + l15) * 72 + qc];
                const float s = (kb < 2) ? snl[i] : csl[i];
                bf16x8 sc;
#pragma unroll
                for (int e = 0; e < 8; e++) sc[e] = (__bf16)((float)raw[e] * s);
                af[i] = sc;
            }
            bf16x8 bf[5];
#pragma unroll
            for (int j = 0; j < 5; j++)
                bf[j] = *(const bf16x8*)&Bs[(j * 16 + l15) * 136 + kb * 32 + quad * 8];
#pragma unroll
            for (int i = 0; i < 2; i++)
#pragma unroll
                for (int j = 0; j < 5; j++)
                    acc[i][j] = __builtin_amdgcn_mfma_f32_16x16x32_bf16(
                        af[i], bf[j], acc[i][j], 0, 0, 0);
        }

        __syncthreads();
#pragma unroll
        for (int i = 0; i < 2; i++) {
            float z[4];
#pragma unroll
            for (int r = 0; r < 4; r++) {
                const float den = __shfl(acc[i][4][r], lane & 0x30, 64);
                z[r] = 1.0f / fmaxf(den, EPS_Z);
            }
#pragma unroll
            for (int j = 0; j < 4; j++)
#pragma unroll
                for (int r = 0; r < 4; r++) {
                    const int row = wm + i * 16 + quad * 4 + r;
                    As[row * 64 + j * 16 + l15] = f32_to_bf16(acc[i][j][r] * z[r]);
                }
        }
        __syncthreads();
        const int rloc = tid >> 3, c8o = (tid & 7) * 8;
#pragma unroll
        for (int it = 0; it < 4; ++it) {
            const int row = it * 32 + rloc;
            uint4 t4 = *(const uint4*)&As[row * 64 + c8o];
            *(uint4*)&merged[(b4 + tm + row) * 1024 + h * 64 + c8o] = t4;
        }
    }
}

// ---------------------------------------------------------------------------
extern "C" void kernel_launch(void* const* d_in, const int* in_sizes, int n_in,
                              void* d_out, int out_size, void* d_ws, size_t ws_size,
                              hipStream_t stream) {
    (void)in_sizes; (void)n_in; (void)out_size; (void)ws_size;
    const float* x  = (const float*)d_in[0];
    const float* Wq = (const float*)d_in[1];
    const float* bq = (const float*)d_in[2];
    const float* Wk = (const float*)d_in[3];
    const float* bk = (const float*)d_in[4];
    const float* Wv = (const float*)d_in[5];
    const float* bv = (const float*)d_in[6];
    const float* Wo = (const float*)d_in[7];
    const float* bo = (const float*)d_in[8];
    float* out = (float*)d_out;

    const int E = 1024;
    char* ws = (char*)d_ws;
    const size_t MB = 1048576;
    float* part = (float*)(ws);          // 20 MiB (x no longer staged)
    u16* qb   = (u16*)(ws + 32 * MB);
    u16* kb   = (u16*)(ws + 64 * MB);    // dead after kv_mfma -> merged
    u16* vb   = (u16*)(ws + 96 * MB);
    u16* wcat = (u16*)(ws + 128 * MB);   // Wq;Wk;Wv;Wo bf16, 8 MiB
    u16* wob  = wcat + 3 * (size_t)E * E;
    u16* Btb  = (u16*)(ws + 136 * MB);   // 1.25 MiB
    u16* mergedb = kb;

    cvt_w4<<<dim3(1024, 4), dim3(256), 0, stream>>>(Wq, Wk, Wv, Wo, wcat);

    gemm_qkv<<<dim3(768), dim3(512), 0, stream>>>(x, wcat, bq, bk, bv, qb, kb, vb);

    kv_mfma<<<dim3(8, 64), dim3(256), 0, stream>>>(kb, vb, part);
    kv_reduce_t<<<dim3(4, 64), dim3(256), 0, stream>>>(part, Btb);
    attn_mfma<<<dim3(16, 64), dim3(256), 0, stream>>>(qb, Btb, mergedb);

    gemm_o<<<dim3(256), dim3(512), 0, stream>>>(mergedb, wob, bo, out);
}

// Round 9
// 344.965 us; speedup vs baseline: 1.0946x; 1.0946x over previous
//
#include <hip/hip_runtime.h>

// ---------------------------------------------------------------------------
// MultiheadCosformerAttention: B=4, L=4096, E=1024, H=16, hd=64
// Round 13: fp32-A reg-staging reverted (vmcnt pollution -> 189us). Full
//           revert to round-10 best (341.1us): fused cvt, bf16 gload_lds
//           2-barrier counted-vmcnt GEMM core, bounce epilogues, 64-l kv
//           tiles, 256-row attn. One safe change: kv chunks 8 -> 4
//           (halves the 20MB part round-trip; 256 blocks still fill CUs).
// ---------------------------------------------------------------------------

typedef unsigned short u16;
typedef unsigned int u32;
typedef __attribute__((ext_vector_type(8))) __bf16 bf16x8;
typedef __attribute__((ext_vector_type(4))) float f32x4;

#define PI_HALF 1.57079632679489662f
#define EPS_Z 1e-4f

__device__ __forceinline__ u16 f32_to_bf16(float f) {
    union { float f; unsigned int u; } x; x.f = f;
    unsigned int lsb = (x.u >> 16) & 1u;
    x.u += 0x7fffu + lsb;                 // round-to-nearest-even
    return (u16)(x.u >> 16);
}

typedef __attribute__((address_space(1))) void amdgpu_global_t;
typedef __attribute__((address_space(3))) void amdgpu_lds_t;
__device__ __forceinline__ void async_load16(const u16* g, u16* l) {
    __builtin_amdgcn_global_load_lds((amdgpu_global_t*)g, (amdgpu_lds_t*)l, 16, 0, 0);
}

// ---------------------------------------------------------------------------
// fp32 -> bf16 converts, fused: blocks [0,16384) do x, [16384, 20480) do the
// four weight matrices into wcat.
// ---------------------------------------------------------------------------
__global__ __launch_bounds__(256) void cvt_all(const float* __restrict__ x,
                                               const float* __restrict__ w0,
                                               const float* __restrict__ w1,
                                               const float* __restrict__ w2,
                                               const float* __restrict__ w3,
                                               u16* __restrict__ xb,
                                               u16* __restrict__ wcat) {
    const int bid = blockIdx.x;
    const float* src;
    u16* dst;
    int i;
    if (bid < 16384) {
        src = x; dst = xb;
        i = bid * 256 + threadIdx.x;
    } else {
        const int wb = bid - 16384;
        const int wsel = wb >> 10;            // 1024 blocks per weight
        src = (wsel == 0) ? w0 : (wsel == 1) ? w1 : (wsel == 2) ? w2 : w3;
        dst = wcat + (size_t)wsel * 1048576;
        i = (wb & 1023) * 256 + threadIdx.x;
    }
    float4 f = ((const float4*)src)[i];
    ushort4 o;
    o.x = f32_to_bf16(f.x); o.y = f32_to_bf16(f.y);
    o.z = f32_to_bf16(f.z); o.w = f32_to_bf16(f.w);
    ((ushort4*)dst)[i] = o;
}

// ---------------------------------------------------------------------------
// 256x256 / BK=64 / 8-wave GEMM core, 2 barriers per K-tile (A and B K-major,
// K = 1024, 16 K-tiles). LDS 128 KiB double-buffered; XOR swizzle via
// pre-swizzled global source (bank-conflict-free at 1.57e6/dispatch,
// epilogue-only). Best verified configuration (341.1 us total).
// ---------------------------------------------------------------------------
__device__ __forceinline__ void gemm256_core(const u16* __restrict__ Abase,
                                             const u16* __restrict__ Bbase,
                                             u16* As, u16* Bs,
                                             f32x4 (&acc)[8][4]) {
    const int tid  = threadIdx.x;
    const int wave = tid >> 6;
    const int lane = tid & 63;
    const int quad = lane >> 4;
    const int l15  = lane & 15;
    const int wr   = wave >> 2;
    const int wc   = wave & 3;
    const int srow = tid >> 3;
    const int scg  = (tid & 7) ^ (srow & 7);

    const u16* Ag = Abase + ((long)srow << 10) + scg * 8;
    const u16* Bg = Bbase + ((long)srow << 10) + scg * 8;

    auto stage = [&](const u16* g, u16* lb, int hs, int t) {
        async_load16(g + ((long)hs << 16) + (t << 6), lb + hs * 4096);
    };
    auto rdA = [&](const u16* buf, int mf, int kk) -> bf16x8 {
        const int R = wr * 128 + mf * 16 + l15;
        return *(const bf16x8*)(buf + R * 64 + ((kk * 32 + quad * 8) ^ ((R & 7) * 8)));
    };
    auto rdB = [&](const u16* buf, int nf, int kk) -> bf16x8 {
        const int R = wc * 64 + nf * 16 + l15;
        return *(const bf16x8*)(buf + R * 64 + ((kk * 32 + quad * 8) ^ ((R & 7) * 8)));
    };

    bf16x8 a[4][2], b[4][2];
    auto mfma8 = [&](int i0, int j0) {
        __builtin_amdgcn_s_setprio(1);
#pragma unroll
        for (int i = 0; i < 4; ++i)
#pragma unroll
            for (int j = 0; j < 2; ++j)
#pragma unroll
                for (int kk = 0; kk < 2; ++kk)
                    acc[i0 + i][j0 + j] = __builtin_amdgcn_mfma_f32_16x16x32_bf16(
                        a[i][kk], b[j0 + j][kk], acc[i0 + i][j0 + j], 0, 0, 0);
        __builtin_amdgcn_s_setprio(0);
    };

#pragma unroll
    for (int hs = 0; hs < 4; ++hs) stage(Ag, As + wave * 512, hs, 0);
#pragma unroll
    for (int hs = 0; hs < 4; ++hs) stage(Bg, Bs + wave * 512, hs, 0);
#pragma unroll
    for (int hs = 0; hs < 4; ++hs) stage(Ag, As + 16384 + wave * 512, hs, 1);
#pragma unroll
    for (int hs = 0; hs < 4; ++hs) stage(Bg, Bs + 16384 + wave * 512, hs, 1);
    asm volatile("s_waitcnt vmcnt(8)" ::: "memory");
    __builtin_amdgcn_s_barrier();

#pragma unroll 1
    for (int t = 0; t < 16; ++t) {
        const int cur = t & 1;
        const u16* Ab = As + cur * 16384;
        const u16* Bb = Bs + cur * 16384;
        u16* lA = As + cur * 16384 + wave * 512;
        u16* lB = Bs + cur * 16384 + wave * 512;
        const bool pf = (t < 14);

#pragma unroll
        for (int i = 0; i < 4; ++i) { a[i][0] = rdA(Ab, i, 0); a[i][1] = rdA(Ab, i, 1); }
#pragma unroll
        for (int j = 0; j < 2; ++j) { b[j][0] = rdB(Bb, j, 0); b[j][1] = rdB(Bb, j, 1); }
        mfma8(0, 0);
#pragma unroll
        for (int j = 2; j < 4; ++j) { b[j][0] = rdB(Bb, j, 0); b[j][1] = rdB(Bb, j, 1); }
        mfma8(0, 2);
#pragma unroll
        for (int i = 0; i < 4; ++i) { a[i][0] = rdA(Ab, i + 4, 0); a[i][1] = rdA(Ab, i + 4, 1); }
        mfma8(4, 0);

        __builtin_amdgcn_s_barrier();
        asm volatile("" ::: "memory");
        if (pf) {
#pragma unroll
            for (int hs = 0; hs < 4; ++hs) stage(Bg, lB, hs, t + 2);
#pragma unroll
            for (int hs = 0; hs < 4; ++hs) stage(Ag, lA, hs, t + 2);
        }
        mfma8(4, 2);
        if (pf) {
            asm volatile("s_waitcnt vmcnt(8)" ::: "memory");
        } else {
            asm volatile("s_waitcnt vmcnt(0)" ::: "memory");
        }
        __builtin_amdgcn_s_barrier();
        asm volatile("" ::: "memory");
    }
}

// ---------------------------------------------------------------------------
// Fused QKV GEMM. Wcat = [3072][1024] (Wq;Wk;Wv). Grid: 768 blocks of 512.
// Epilogue: LDS-bounce for fully-coalesced dwordx4 stores (512B runs/row).
// ---------------------------------------------------------------------------
__global__ __launch_bounds__(512, 2) void gemm_qkv(const u16* __restrict__ A,
                                                   const u16* __restrict__ Wcat,
                                                   const float* __restrict__ bq,
                                                   const float* __restrict__ bk,
                                                   const float* __restrict__ bv,
                                                   u16* __restrict__ qo,
                                                   u16* __restrict__ ko,
                                                   u16* __restrict__ vo) {
    __shared__ __align__(16) u16 As[32768];
    __shared__ __align__(16) u16 Bs[32768];
    const int bid = blockIdx.x;                    // 768 = 64 M x 12 N
    const int swz = (bid & 7) * 96 + (bid >> 3);   // XCD swizzle
    const int bx  = swz / 12;
    const int byy = swz - bx * 12;
    const long tileM = (long)bx * 256;

    f32x4 acc[8][4] = {};
    gemm256_core(A + (tileM << 10), Wcat + ((long)byy << 18), As, Bs, acc);

    const int tid  = (int)threadIdx.x;
    const int wave = tid >> 6;
    const int lane = tid & 63;
    const int quad = lane >> 4, l15 = lane & 15;
    const int wr = wave >> 2, wc = wave & 3;
    const int mat = byy >> 2;                      // 0:q 1:k 2:v
    const float* bias = (mat == 0) ? bq : (mat == 1) ? bk : bv;
    u16* outp = (mat == 0) ? qo : (mat == 1) ? ko : vo;
    const bool relu = (mat < 2);
    const int ncol0 = (byy & 3) * 256;

    const int rloc = tid >> 5;
    const int c8   = (tid & 31) * 8;
#pragma unroll 1
    for (int pass = 0; pass < 2; ++pass) {
        __syncthreads();
        if (wr == pass) {
#pragma unroll
            for (int i = 0; i < 8; ++i)
#pragma unroll
                for (int j = 0; j < 4; ++j) {
                    const int col = wc * 64 + j * 16 + l15;
                    const float bb = bias[ncol0 + col];
#pragma unroll
                    for (int r = 0; r < 4; ++r) {
                        const int row = i * 16 + quad * 4 + r;
                        float v = acc[i][j][r] + bb;
                        if (relu) v = fmaxf(v, 0.0f);
                        As[row * 256 + col] = f32_to_bf16(v);
                    }
                }
        }
        __syncthreads();
        const long gr0 = tileM + pass * 128;
#pragma unroll
        for (int it = 0; it < 8; ++it) {
            const int row = it * 16 + rloc;
            uint4 t4 = *(const uint4*)&As[row * 256 + c8];
            *(uint4*)&outp[(gr0 + row) * 1024 + ncol0 + c8] = t4;
        }
    }
}

// ---------------------------------------------------------------------------
// Output-projection GEMM (fp32 out). Grid: 256 blocks of 512.
// ---------------------------------------------------------------------------
__global__ __launch_bounds__(512, 2) void gemm_o(const u16* __restrict__ A,
                                                 const u16* __restrict__ Bw,
                                                 const float* __restrict__ bias,
                                                 float* __restrict__ Cout) {
    __shared__ __align__(16) u16 As[32768];
    __shared__ __align__(16) u16 Bs[32768];
    const int bid = blockIdx.x;
    const int swz = (bid & 7) * 32 + (bid >> 3);
    const long tileM = (long)(swz >> 2) * 256;
    const long tileN = (long)(swz & 3) * 256;

    f32x4 acc[8][4] = {};
    gemm256_core(A + (tileM << 10), Bw + (tileN << 10), As, Bs, acc);

    const int wave = (int)threadIdx.x >> 6;
    const int lane = (int)threadIdx.x & 63;
    const int quad = lane >> 4, l15 = lane & 15;
    const int wr = wave >> 2, wc = wave & 3;
#pragma unroll
    for (int j = 0; j < 4; ++j) {
        const long n = tileN + wc * 64 + j * 16 + l15;
        const float bb = bias[n];
#pragma unroll
        for (int i = 0; i < 8; ++i) {
            const long m0 = tileM + wr * 128 + i * 16 + quad * 4;
#pragma unroll
            for (int r = 0; r < 4; ++r)
                Cout[(m0 + r) * 1024 + n] = acc[i][j][r] + bb;
        }
    }
}

// ---------------------------------------------------------------------------
// Stage C (MFMA): per (chunk, head): part[d2=128][n=80] = k_^T @ [v | 1 | 0].
// 4 chunks of K=1024 l's each (halved part traffic vs 8 chunks); 64-l
// K-tiles; register prefetch of next-kt loads.
// grid (4, 64), 256 threads = 4 waves.
// part layout: [chunk4][head64][128][80] f32.
// ---------------------------------------------------------------------------
__global__ __launch_bounds__(256) void kv_mfma(const u16* __restrict__ kmat,
                                               const u16* __restrict__ vmat,
                                               float* __restrict__ part) {
    __shared__ u16 Ak[64 * 72];   // [d 64][l 64 +8 pad]
    __shared__ u16 Bv[64 * 72];
    const int tid = threadIdx.x;
    const int wave = tid >> 6, lane = tid & 63;
    const int quad = lane >> 4, l15 = lane & 15;
    const int head = blockIdx.y;
    const int b = head >> 4, h = head & 15;
    const int l0 = blockIdx.x * 1024;
    const int sl = tid >> 3;
    const int sc8 = tid & 7;
    const int scol = sl ^ ((sc8 & 3) << 3);
    const int krow_base = (wave & 1) * 32;
    const bool use_cos = (wave >> 1) != 0;
    const int mbase = wave * 32;

    float sv[8], cv[8], s2[8], c2[8];
#pragma unroll
    for (int e = 0; e < 8; e++) {
        float ang = (PI_HALF / 4096.0f) * (float)(l0 + quad * 8 + e + 1);
        sv[e] = sinf(ang); cv[e] = cosf(ang);
        float ang2 = ang + (PI_HALF / 4096.0f) * 32.0f;
        s2[e] = sinf(ang2); c2[e] = cosf(ang2);
    }
    const float cD = 0.99969881869620422f;  // cos(pi/128)
    const float sD = 0.02454122852291229f;  // sin(pi/128)

    bf16x8 onesf;
#pragma unroll
    for (int e = 0; e < 8; e++)
        onesf[e] = (l15 == 0) ? (__bf16)1.0f : (__bf16)0.0f;

    f32x4 acc[2][5] = {};

    long row = ((long)b * 4096 + l0 + sl) * 1024 + h * 64 + sc8 * 8;
    uint4 kkA = *(const uint4*)(kmat + row);
    uint4 vvA = *(const uint4*)(vmat + row);
    uint4 kkB = *(const uint4*)(kmat + row + 32 * 1024);
    uint4 vvB = *(const uint4*)(vmat + row + 32 * 1024);

#pragma unroll 1
    for (int kt = 0; kt < 16; kt++) {
        uint4 kkA_n = {}, vvA_n = {}, kkB_n = {}, vvB_n = {};
        if (kt < 15) {
            row += 64 * 1024;
            kkA_n = *(const uint4*)(kmat + row);
            vvA_n = *(const uint4*)(vmat + row);
            kkB_n = *(const uint4*)(kmat + row + 32 * 1024);
            vvB_n = *(const uint4*)(vmat + row + 32 * 1024);
        }
        {
            const u16* kp = (const u16*)&kkA;
            const u16* vp = (const u16*)&vvA;
            const u16* kp2 = (const u16*)&kkB;
            const u16* vp2 = (const u16*)&vvB;
#pragma unroll
            for (int e = 0; e < 8; e++) {
                const int d = sc8 * 8 + e;
                Ak[d * 72 + scol]      = kp[e];
                Bv[d * 72 + scol]      = vp[e];
                Ak[d * 72 + scol + 32] = kp2[e];
                Bv[d * 72 + scol + 32] = vp2[e];
            }
        }
        __syncthreads();

        bf16x8 af[2][2];
#pragma unroll
        for (int i = 0; i < 2; i++) {
            const int d = krow_base + i * 16 + l15;
            const int q2 = (quad ^ ((d >> 3) & 3)) * 8;
#pragma unroll
            for (int kk = 0; kk < 2; kk++) {
                bf16x8 raw = *(const bf16x8*)&Ak[d * 72 + kk * 32 + q2];
                bf16x8 sc;
#pragma unroll
                for (int e = 0; e < 8; e++) {
                    const float s = use_cos ? (kk ? c2[e] : cv[e])
                                            : (kk ? s2[e] : sv[e]);
                    sc[e] = (__bf16)((float)raw[e] * s);
                }
                af[i][kk] = sc;
            }
        }
        bf16x8 bfr[5][2];
#pragma unroll
        for (int j = 0; j < 4; j++) {
            const int n = j * 16 + l15;
            const int q2 = (quad ^ ((n >> 3) & 3)) * 8;
            bfr[j][0] = *(const bf16x8*)&Bv[n * 72 + q2];
            bfr[j][1] = *(const bf16x8*)&Bv[n * 72 + 32 + q2];
        }
        bfr[4][0] = onesf; bfr[4][1] = onesf;
#pragma unroll
        for (int i = 0; i < 2; i++)
#pragma unroll
            for (int j = 0; j < 5; j++) {
                acc[i][j] = __builtin_amdgcn_mfma_f32_16x16x32_bf16(
                    af[i][0], bfr[j][0], acc[i][j], 0, 0, 0);
                acc[i][j] = __builtin_amdgcn_mfma_f32_16x16x32_bf16(
                    af[i][1], bfr[j][1], acc[i][j], 0, 0, 0);
            }

#pragma unroll
        for (int e = 0; e < 8; e++) {
            float ns = sv[e] * cD + cv[e] * sD;
            cv[e] = cv[e] * cD - sv[e] * sD;
            sv[e] = ns;
            ns = s2[e] * cD + c2[e] * sD;
            c2[e] = c2[e] * cD - s2[e] * sD;
            s2[e] = ns;
        }
        __syncthreads();
        kkA = kkA_n; vvA = vvA_n; kkB = kkB_n; vvB = vvB_n;
    }

    float* op = part + ((long)blockIdx.x * 64 + head) * 10240;
#pragma unroll
    for (int i = 0; i < 2; i++)
#pragma unroll
        for (int j = 0; j < 5; j++)
#pragma unroll
            for (int r = 0; r < 4; r++)
                op[(mbase + i * 16 + quad * 4 + r) * 80 + j * 16 + l15] = acc[i][j][r];
}

// ---------------------------------------------------------------------------
// Stage C2: sum 4 chunk-partials, transpose to Bt[head][n=80][d2=128] bf16.
// grid (4 d2-tiles of 32, 64 heads), 256 threads.
// ---------------------------------------------------------------------------
__global__ __launch_bounds__(256) void kv_reduce_t(const float* __restrict__ part,
                                                   u16* __restrict__ Bt) {
    __shared__ float accs[32 * 81];
    const int head = blockIdx.y, d2t = blockIdx.x;
    const float* bp = part + (long)head * 10240 + d2t * 32 * 80;
    for (int idx = threadIdx.x; idx < 2560; idx += 256) {
        float s = 0.0f;
#pragma unroll
        for (int c = 0; c < 4; c++) s += bp[(long)c * 655360 + idx];
        const int d2 = idx / 80, n = idx - d2 * 80;
        accs[d2 * 81 + n] = s;
    }
    __syncthreads();
    for (int idx = threadIdx.x; idx < 2560; idx += 256) {
        const int n = idx >> 5, d2 = idx & 31;
        Bt[(long)head * 10240 + n * 128 + d2t * 32 + d2] = f32_to_bf16(accs[d2 * 81 + n]);
    }
}

// ---------------------------------------------------------------------------
// Stage D: per-head MFMA GEMM: attn[l, 0..79] = q_[l, 0..127] @ Bt^T
// 256 q-rows per block (Bt staged once per 2 q-tiles).
// grid (16, 64), 256 threads.
// ---------------------------------------------------------------------------
__global__ __launch_bounds__(256) void attn_mfma(const u16* __restrict__ qb,
                                                 const u16* __restrict__ Bt,
                                                 u16* __restrict__ merged) {
    __shared__ __align__(16) u16 As[128 * 72];
    __shared__ __align__(16) u16 Bs[80 * 136];
    const int tid = threadIdx.x;
    const int wave = tid >> 6, lane = tid & 63;
    const int quad = lane >> 4, l15 = lane & 15;
    const int head = blockIdx.y;
    const int b = head >> 4, h = head & 15;
    const int tm0 = blockIdx.x * 256;
    const long b4 = (long)b * 4096;
    const int wm = wave * 32;

    for (int c = tid; c < 1280; c += 256) {
        const int row = c >> 4, c16 = c & 15;
        uint4 t = *(const uint4*)(Bt + (long)head * 10240 + row * 128 + c16 * 8);
        *(uint4*)&Bs[row * 136 + c16 * 8] = t;
    }

#pragma unroll 1
    for (int half = 0; half < 2; ++half) {
        const int tm = tm0 + half * 128;
        __syncthreads();
        for (int c = tid; c < 1024; c += 256) {
            const int row = c >> 3, c8 = c & 7;
            uint4 t = *(const uint4*)(qb + (b4 + tm + row) * 1024 + h * 64 + c8 * 8);
            *(uint4*)&As[row * 72 + c8 * 8] = t;
        }
        float snl[2], csl[2];
#pragma unroll
        for (int i = 0; i < 2; i++) {
            const int l = tm + wm + i * 16 + l15;
            const float idx = PI_HALF * (float)(l + 1) * (1.0f / 4096.0f);
            snl[i] = sinf(idx); csl[i] = cosf(idx);
        }
        __syncthreads();

        f32x4 acc[2][5] = {};
#pragma unroll
        for (int kb = 0; kb < 4; kb++) {
            const int qc = (kb & 1) * 32 + quad * 8;
            bf16x8 af[2];
#pragma unroll
            for (int i = 0; i < 2; i++) {
                bf16x8 raw = *(const bf16x8*)&As[(wm + i * 16 + l15) * 72 + qc];
                const float s = (kb < 2) ? snl[i] : csl[i];
                bf16x8 sc;
#pragma unroll
                for (int e = 0; e < 8; e++) sc[e] = (__bf16)((float)raw[e] * s);
                af[i] = sc;
            }
            bf16x8 bf[5];
#pragma unroll
            for (int j = 0; j < 5; j++)
                bf[j] = *(const bf16x8*)&Bs[(j * 16 + l15) * 136 + kb * 32 + quad * 8];
#pragma unroll
            for (int i = 0; i < 2; i++)
#pragma unroll
                for (int j = 0; j < 5; j++)
                    acc[i][j] = __builtin_amdgcn_mfma_f32_16x16x32_bf16(
                        af[i], bf[j], acc[i][j], 0, 0, 0);
        }

        __syncthreads();
#pragma unroll
        for (int i = 0; i < 2; i++) {
            float z[4];
#pragma unroll
            for (int r = 0; r < 4; r++) {
                const float den = __shfl(acc[i][4][r], lane & 0x30, 64);
                z[r] = 1.0f / fmaxf(den, EPS_Z);
            }
#pragma unroll
            for (int j = 0; j < 4; j++)
#pragma unroll
                for (int r = 0; r < 4; r++) {
                    const int row = wm + i * 16 + quad * 4 + r;
                    As[row * 64 + j * 16 + l15] = f32_to_bf16(acc[i][j][r] * z[r]);
                }
        }
        __syncthreads();
        const int rloc = tid >> 3, c8o = (tid & 7) * 8;
#pragma unroll
        for (int it = 0; it < 4; ++it) {
            const int row = it * 32 + rloc;
            uint4 t4 = *(const uint4*)&As[row * 64 + c8o];
            *(uint4*)&merged[(b4 + tm + row) * 1024 + h * 64 + c8o] = t4;
        }
    }
}

// ---------------------------------------------------------------------------
extern "C" void kernel_launch(void* const* d_in, const int* in_sizes, int n_in,
                              void* d_out, int out_size, void* d_ws, size_t ws_size,
                              hipStream_t stream) {
    (void)in_sizes; (void)n_in; (void)out_size; (void)ws_size;
    const float* x  = (const float*)d_in[0];
    const float* Wq = (const float*)d_in[1];
    const float* bq = (const float*)d_in[2];
    const float* Wk = (const float*)d_in[3];
    const float* bk = (const float*)d_in[4];
    const float* Wv = (const float*)d_in[5];
    const float* bv = (const float*)d_in[6];
    const float* Wo = (const float*)d_in[7];
    const float* bo = (const float*)d_in[8];
    float* out = (float*)d_out;

    const int M = 16384, E = 1024;
    char* ws = (char*)d_ws;
    const size_t MB = 1048576;
    u16* xb   = (u16*)(ws);              // 32 MiB; dead after QKV GEMM -> part
    u16* qb   = (u16*)(ws + 32 * MB);
    u16* kb   = (u16*)(ws + 64 * MB);    // dead after kv_mfma -> merged
    u16* vb   = (u16*)(ws + 96 * MB);
    u16* wcat = (u16*)(ws + 128 * MB);   // Wq;Wk;Wv;Wo bf16, 8 MiB
    u16* wob  = wcat + 3 * (size_t)E * E;
    u16* Btb  = (u16*)(ws + 136 * MB);   // 1.25 MiB
    float* part = (float*)xb;            // 4*64*10240*4 = 10 MiB
    u16* mergedb = kb;

    cvt_all<<<dim3(20480), dim3(256), 0, stream>>>(x, Wq, Wk, Wv, Wo, xb, wcat);

    gemm_qkv<<<dim3(768), dim3(512), 0, stream>>>(xb, wcat, bq, bk, bv, qb, kb, vb);

    kv_mfma<<<dim3(4, 64), dim3(256), 0, stream>>>(kb, vb, part);
    kv_reduce_t<<<dim3(4, 64), dim3(256), 0, stream>>>(part, Btb);
    attn_mfma<<<dim3(16, 64), dim3(256), 0, stream>>>(qb, Btb, mergedb);

    gemm_o<<<dim3(256), dim3(512), 0, stream>>>(mergedb, wob, bo, out);
}

// Round 10
// 343.788 us; speedup vs baseline: 1.0984x; 1.0034x over previous
//
#include <hip/hip_runtime.h>

// ---------------------------------------------------------------------------
// MultiheadCosformerAttention: B=4, L=4096, E=1024, H=16, hd=64
// Round 14: restore the verified-best round-10 configuration (341.1 us):
//           fused cvt, bf16 gload_lds 2-barrier counted-vmcnt 256^2 GEMM
//           core, bounce epilogues, kv 8 chunks (2 blocks/CU), 64-l kv tiles,
//           256-row attn. One safe change: cvt_all grid-strided at 2048
//           blocks (G11) instead of 20480 one-shot blocks.
// ---------------------------------------------------------------------------

typedef unsigned short u16;
typedef unsigned int u32;
typedef __attribute__((ext_vector_type(8))) __bf16 bf16x8;
typedef __attribute__((ext_vector_type(4))) float f32x4;

#define PI_HALF 1.57079632679489662f
#define EPS_Z 1e-4f

__device__ __forceinline__ u16 f32_to_bf16(float f) {
    union { float f; unsigned int u; } x; x.f = f;
    unsigned int lsb = (x.u >> 16) & 1u;
    x.u += 0x7fffu + lsb;                 // round-to-nearest-even
    return (u16)(x.u >> 16);
}

typedef __attribute__((address_space(1))) void amdgpu_global_t;
typedef __attribute__((address_space(3))) void amdgpu_lds_t;
__device__ __forceinline__ void async_load16(const u16* g, u16* l) {
    __builtin_amdgcn_global_load_lds((amdgpu_global_t*)g, (amdgpu_lds_t*)l, 16, 0, 0);
}

// ---------------------------------------------------------------------------
// fp32 -> bf16 converts, fused + grid-strided (2048 blocks, ~10 iters/thread).
// vec4 index space: [0, 4194304) = x, then 4 x 262144 = weights.
// ---------------------------------------------------------------------------
__global__ __launch_bounds__(256) void cvt_all(const float* __restrict__ x,
                                               const float* __restrict__ w0,
                                               const float* __restrict__ w1,
                                               const float* __restrict__ w2,
                                               const float* __restrict__ w3,
                                               u16* __restrict__ xb,
                                               u16* __restrict__ wcat) {
    const int XN  = 4194304;             // 16384*1024/4
    const int TOT = 5242880;             // + 4*262144
    for (int i = blockIdx.x * 256 + threadIdx.x; i < TOT; i += gridDim.x * 256) {
        const float* src; u16* dst; int j;
        if (i < XN) {
            src = x; dst = xb; j = i;
        } else {
            const int wi = i - XN;
            const int wsel = wi >> 18;   // 262144 vec4 per weight
            src = (wsel == 0) ? w0 : (wsel == 1) ? w1 : (wsel == 2) ? w2 : w3;
            dst = wcat + (size_t)wsel * 1048576;
            j = wi & 262143;
        }
        float4 f = ((const float4*)src)[j];
        ushort4 o;
        o.x = f32_to_bf16(f.x); o.y = f32_to_bf16(f.y);
        o.z = f32_to_bf16(f.z); o.w = f32_to_bf16(f.w);
        ((ushort4*)dst)[j] = o;
    }
}

// ---------------------------------------------------------------------------
// 256x256 / BK=64 / 8-wave GEMM core, 2 barriers per K-tile (A and B K-major,
// K = 1024, 16 K-tiles). LDS 128 KiB double-buffered; XOR swizzle via
// pre-swizzled global source. Best verified configuration.
// ---------------------------------------------------------------------------
__device__ __forceinline__ void gemm256_core(const u16* __restrict__ Abase,
                                             const u16* __restrict__ Bbase,
                                             u16* As, u16* Bs,
                                             f32x4 (&acc)[8][4]) {
    const int tid  = threadIdx.x;
    const int wave = tid >> 6;
    const int lane = tid & 63;
    const int quad = lane >> 4;
    const int l15  = lane & 15;
    const int wr   = wave >> 2;
    const int wc   = wave & 3;
    const int srow = tid >> 3;
    const int scg  = (tid & 7) ^ (srow & 7);

    const u16* Ag = Abase + ((long)srow << 10) + scg * 8;
    const u16* Bg = Bbase + ((long)srow << 10) + scg * 8;

    auto stage = [&](const u16* g, u16* lb, int hs, int t) {
        async_load16(g + ((long)hs << 16) + (t << 6), lb + hs * 4096);
    };
    auto rdA = [&](const u16* buf, int mf, int kk) -> bf16x8 {
        const int R = wr * 128 + mf * 16 + l15;
        return *(const bf16x8*)(buf + R * 64 + ((kk * 32 + quad * 8) ^ ((R & 7) * 8)));
    };
    auto rdB = [&](const u16* buf, int nf, int kk) -> bf16x8 {
        const int R = wc * 64 + nf * 16 + l15;
        return *(const bf16x8*)(buf + R * 64 + ((kk * 32 + quad * 8) ^ ((R & 7) * 8)));
    };

    bf16x8 a[4][2], b[4][2];
    auto mfma8 = [&](int i0, int j0) {
        __builtin_amdgcn_s_setprio(1);
#pragma unroll
        for (int i = 0; i < 4; ++i)
#pragma unroll
            for (int j = 0; j < 2; ++j)
#pragma unroll
                for (int kk = 0; kk < 2; ++kk)
                    acc[i0 + i][j0 + j] = __builtin_amdgcn_mfma_f32_16x16x32_bf16(
                        a[i][kk], b[j0 + j][kk], acc[i0 + i][j0 + j], 0, 0, 0);
        __builtin_amdgcn_s_setprio(0);
    };

#pragma unroll
    for (int hs = 0; hs < 4; ++hs) stage(Ag, As + wave * 512, hs, 0);
#pragma unroll
    for (int hs = 0; hs < 4; ++hs) stage(Bg, Bs + wave * 512, hs, 0);
#pragma unroll
    for (int hs = 0; hs < 4; ++hs) stage(Ag, As + 16384 + wave * 512, hs, 1);
#pragma unroll
    for (int hs = 0; hs < 4; ++hs) stage(Bg, Bs + 16384 + wave * 512, hs, 1);
    asm volatile("s_waitcnt vmcnt(8)" ::: "memory");
    __builtin_amdgcn_s_barrier();

#pragma unroll 1
    for (int t = 0; t < 16; ++t) {
        const int cur = t & 1;
        const u16* Ab = As + cur * 16384;
        const u16* Bb = Bs + cur * 16384;
        u16* lA = As + cur * 16384 + wave * 512;
        u16* lB = Bs + cur * 16384 + wave * 512;
        const bool pf = (t < 14);

#pragma unroll
        for (int i = 0; i < 4; ++i) { a[i][0] = rdA(Ab, i, 0); a[i][1] = rdA(Ab, i, 1); }
#pragma unroll
        for (int j = 0; j < 2; ++j) { b[j][0] = rdB(Bb, j, 0); b[j][1] = rdB(Bb, j, 1); }
        mfma8(0, 0);
#pragma unroll
        for (int j = 2; j < 4; ++j) { b[j][0] = rdB(Bb, j, 0); b[j][1] = rdB(Bb, j, 1); }
        mfma8(0, 2);
#pragma unroll
        for (int i = 0; i < 4; ++i) { a[i][0] = rdA(Ab, i + 4, 0); a[i][1] = rdA(Ab, i + 4, 1); }
        mfma8(4, 0);

        __builtin_amdgcn_s_barrier();
        asm volatile("" ::: "memory");
        if (pf) {
#pragma unroll
            for (int hs = 0; hs < 4; ++hs) stage(Bg, lB, hs, t + 2);
#pragma unroll
            for (int hs = 0; hs < 4; ++hs) stage(Ag, lA, hs, t + 2);
        }
        mfma8(4, 2);
        if (pf) {
            asm volatile("s_waitcnt vmcnt(8)" ::: "memory");
        } else {
            asm volatile("s_waitcnt vmcnt(0)" ::: "memory");
        }
        __builtin_amdgcn_s_barrier();
        asm volatile("" ::: "memory");
    }
}

// ---------------------------------------------------------------------------
// Fused QKV GEMM. Wcat = [3072][1024] (Wq;Wk;Wv). Grid: 768 blocks of 512.
// Epilogue: LDS-bounce for fully-coalesced dwordx4 stores (512B runs/row).
// ---------------------------------------------------------------------------
__global__ __launch_bounds__(512, 2) void gemm_qkv(const u16* __restrict__ A,
                                                   const u16* __restrict__ Wcat,
                                                   const float* __restrict__ bq,
                                                   const float* __restrict__ bk,
                                                   const float* __restrict__ bv,
                                                   u16* __restrict__ qo,
                                                   u16* __restrict__ ko,
                                                   u16* __restrict__ vo) {
    __shared__ __align__(16) u16 As[32768];
    __shared__ __align__(16) u16 Bs[32768];
    const int bid = blockIdx.x;                    // 768 = 64 M x 12 N
    const int swz = (bid & 7) * 96 + (bid >> 3);   // XCD swizzle
    const int bx  = swz / 12;
    const int byy = swz - bx * 12;
    const long tileM = (long)bx * 256;

    f32x4 acc[8][4] = {};
    gemm256_core(A + (tileM << 10), Wcat + ((long)byy << 18), As, Bs, acc);

    const int tid  = (int)threadIdx.x;
    const int wave = tid >> 6;
    const int lane = tid & 63;
    const int quad = lane >> 4, l15 = lane & 15;
    const int wr = wave >> 2, wc = wave & 3;
    const int mat = byy >> 2;                      // 0:q 1:k 2:v
    const float* bias = (mat == 0) ? bq : (mat == 1) ? bk : bv;
    u16* outp = (mat == 0) ? qo : (mat == 1) ? ko : vo;
    const bool relu = (mat < 2);
    const int ncol0 = (byy & 3) * 256;

    const int rloc = tid >> 5;
    const int c8   = (tid & 31) * 8;
#pragma unroll 1
    for (int pass = 0; pass < 2; ++pass) {
        __syncthreads();
        if (wr == pass) {
#pragma unroll
            for (int i = 0; i < 8; ++i)
#pragma unroll
                for (int j = 0; j < 4; ++j) {
                    const int col = wc * 64 + j * 16 + l15;
                    const float bb = bias[ncol0 + col];
#pragma unroll
                    for (int r = 0; r < 4; ++r) {
                        const int row = i * 16 + quad * 4 + r;
                        float v = acc[i][j][r] + bb;
                        if (relu) v = fmaxf(v, 0.0f);
                        As[row * 256 + col] = f32_to_bf16(v);
                    }
                }
        }
        __syncthreads();
        const long gr0 = tileM + pass * 128;
#pragma unroll
        for (int it = 0; it < 8; ++it) {
            const int row = it * 16 + rloc;
            uint4 t4 = *(const uint4*)&As[row * 256 + c8];
            *(uint4*)&outp[(gr0 + row) * 1024 + ncol0 + c8] = t4;
        }
    }
}

// ---------------------------------------------------------------------------
// Output-projection GEMM (fp32 out). Grid: 256 blocks of 512.
// ---------------------------------------------------------------------------
__global__ __launch_bounds__(512, 2) void gemm_o(const u16* __restrict__ A,
                                                 const u16* __restrict__ Bw,
                                                 const float* __restrict__ bias,
                                                 float* __restrict__ Cout) {
    __shared__ __align__(16) u16 As[32768];
    __shared__ __align__(16) u16 Bs[32768];
    const int bid = blockIdx.x;
    const int swz = (bid & 7) * 32 + (bid >> 3);
    const long tileM = (long)(swz >> 2) * 256;
    const long tileN = (long)(swz & 3) * 256;

    f32x4 acc[8][4] = {};
    gemm256_core(A + (tileM << 10), Bw + (tileN << 10), As, Bs, acc);

    const int wave = (int)threadIdx.x >> 6;
    const int lane = (int)threadIdx.x & 63;
    const int quad = lane >> 4, l15 = lane & 15;
    const int wr = wave >> 2, wc = wave & 3;
#pragma unroll
    for (int j = 0; j < 4; ++j) {
        const long n = tileN + wc * 64 + j * 16 + l15;
        const float bb = bias[n];
#pragma unroll
        for (int i = 0; i < 8; ++i) {
            const long m0 = tileM + wr * 128 + i * 16 + quad * 4;
#pragma unroll
            for (int r = 0; r < 4; ++r)
                Cout[(m0 + r) * 1024 + n] = acc[i][j][r] + bb;
        }
    }
}

// ---------------------------------------------------------------------------
// Stage C (MFMA): per (chunk, head): part[d2=128][n=80] = k_^T @ [v | 1 | 0]
//   over K = 512 l's. 64-l K-tiles; register prefetch of next-kt loads.
// grid (8, 64), 256 threads = 4 waves (2 blocks/CU).
// part layout: [chunk8][head64][128][80] f32.
// ---------------------------------------------------------------------------
__global__ __launch_bounds__(256) void kv_mfma(const u16* __restrict__ kmat,
                                               const u16* __restrict__ vmat,
                                               float* __restrict__ part) {
    __shared__ u16 Ak[64 * 72];   // [d 64][l 64 +8 pad]
    __shared__ u16 Bv[64 * 72];
    const int tid = threadIdx.x;
    const int wave = tid >> 6, lane = tid & 63;
    const int quad = lane >> 4, l15 = lane & 15;
    const int head = blockIdx.y;
    const int b = head >> 4, h = head & 15;
    const int l0 = blockIdx.x * 512;
    const int sl = tid >> 3;
    const int sc8 = tid & 7;
    const int scol = sl ^ ((sc8 & 3) << 3);
    const int krow_base = (wave & 1) * 32;
    const bool use_cos = (wave >> 1) != 0;
    const int mbase = wave * 32;

    float sv[8], cv[8], s2[8], c2[8];
#pragma unroll
    for (int e = 0; e < 8; e++) {
        float ang = (PI_HALF / 4096.0f) * (float)(l0 + quad * 8 + e + 1);
        sv[e] = sinf(ang); cv[e] = cosf(ang);
        float ang2 = ang + (PI_HALF / 4096.0f) * 32.0f;
        s2[e] = sinf(ang2); c2[e] = cosf(ang2);
    }
    const float cD = 0.99969881869620422f;  // cos(pi/128)
    const float sD = 0.02454122852291229f;  // sin(pi/128)

    bf16x8 onesf;
#pragma unroll
    for (int e = 0; e < 8; e++)
        onesf[e] = (l15 == 0) ? (__bf16)1.0f : (__bf16)0.0f;

    f32x4 acc[2][5] = {};

    long row = ((long)b * 4096 + l0 + sl) * 1024 + h * 64 + sc8 * 8;
    uint4 kkA = *(const uint4*)(kmat + row);
    uint4 vvA = *(const uint4*)(vmat + row);
    uint4 kkB = *(const uint4*)(kmat + row + 32 * 1024);
    uint4 vvB = *(const uint4*)(vmat + row + 32 * 1024);

#pragma unroll 1
    for (int kt = 0; kt < 8; kt++) {
        uint4 kkA_n = {}, vvA_n = {}, kkB_n = {}, vvB_n = {};
        if (kt < 7) {
            row += 64 * 1024;
            kkA_n = *(const uint4*)(kmat + row);
            vvA_n = *(const uint4*)(vmat + row);
            kkB_n = *(const uint4*)(kmat + row + 32 * 1024);
            vvB_n = *(const uint4*)(vmat + row + 32 * 1024);
        }
        {
            const u16* kp = (const u16*)&kkA;
            const u16* vp = (const u16*)&vvA;
            const u16* kp2 = (const u16*)&kkB;
            const u16* vp2 = (const u16*)&vvB;
#pragma unroll
            for (int e = 0; e < 8; e++) {
                const int d = sc8 * 8 + e;
                Ak[d * 72 + scol]      = kp[e];
                Bv[d * 72 + scol]      = vp[e];
                Ak[d * 72 + scol + 32] = kp2[e];
                Bv[d * 72 + scol + 32] = vp2[e];
            }
        }
        __syncthreads();

        bf16x8 af[2][2];
#pragma unroll
        for (int i = 0; i < 2; i++) {
            const int d = krow_base + i * 16 + l15;
            const int q2 = (quad ^ ((d >> 3) & 3)) * 8;
#pragma unroll
            for (int kk = 0; kk < 2; kk++) {
                bf16x8 raw = *(const bf16x8*)&Ak[d * 72 + kk * 32 + q2];
                bf16x8 sc;
#pragma unroll
                for (int e = 0; e < 8; e++) {
                    const float s = use_cos ? (kk ? c2[e] : cv[e])
                                            : (kk ? s2[e] : sv[e]);
                    sc[e] = (__bf16)((float)raw[e] * s);
                }
                af[i][kk] = sc;
            }
        }
        bf16x8 bfr[5][2];
#pragma unroll
        for (int j = 0; j < 4; j++) {
            const int n = j * 16 + l15;
            const int q2 = (quad ^ ((n >> 3) & 3)) * 8;
            bfr[j][0] = *(const bf16x8*)&Bv[n * 72 + q2];
            bfr[j][1] = *(const bf16x8*)&Bv[n * 72 + 32 + q2];
        }
        bfr[4][0] = onesf; bfr[4][1] = onesf;
#pragma unroll
        for (int i = 0; i < 2; i++)
#pragma unroll
            for (int j = 0; j < 5; j++) {
                acc[i][j] = __builtin_amdgcn_mfma_f32_16x16x32_bf16(
                    af[i][0], bfr[j][0], acc[i][j], 0, 0, 0);
                acc[i][j] = __builtin_amdgcn_mfma_f32_16x16x32_bf16(
                    af[i][1], bfr[j][1], acc[i][j], 0, 0, 0);
            }

#pragma unroll
        for (int e = 0; e < 8; e++) {
            float ns = sv[e] * cD + cv[e] * sD;
            cv[e] = cv[e] * cD - sv[e] * sD;
            sv[e] = ns;
            ns = s2[e] * cD + c2[e] * sD;
            c2[e] = c2[e] * cD - s2[e] * sD;
            s2[e] = ns;
        }
        __syncthreads();
        kkA = kkA_n; vvA = vvA_n; kkB = kkB_n; vvB = vvB_n;
    }

    float* op = part + ((long)blockIdx.x * 64 + head) * 10240;
#pragma unroll
    for (int i = 0; i < 2; i++)
#pragma unroll
        for (int j = 0; j < 5; j++)
#pragma unroll
            for (int r = 0; r < 4; r++)
                op[(mbase + i * 16 + quad * 4 + r) * 80 + j * 16 + l15] = acc[i][j][r];
}

// ---------------------------------------------------------------------------
// Stage C2: sum 8 chunk-partials, transpose to Bt[head][n=80][d2=128] bf16.
// grid (4 d2-tiles of 32, 64 heads), 256 threads.
// ---------------------------------------------------------------------------
__global__ __launch_bounds__(256) void kv_reduce_t(const float* __restrict__ part,
                                                   u16* __restrict__ Bt) {
    __shared__ float accs[32 * 81];
    const int head = blockIdx.y, d2t = blockIdx.x;
    const float* bp = part + (long)head * 10240 + d2t * 32 * 80;
    for (int idx = threadIdx.x; idx < 2560; idx += 256) {
        float s = 0.0f;
#pragma unroll
        for (int c = 0; c < 8; c++) s += bp[(long)c * 655360 + idx];
        const int d2 = idx / 80, n = idx - d2 * 80;
        accs[d2 * 81 + n] = s;
    }
    __syncthreads();
    for (int idx = threadIdx.x; idx < 2560; idx += 256) {
        const int n = idx >> 5, d2 = idx & 31;
        Bt[(long)head * 10240 + n * 128 + d2t * 32 + d2] = f32_to_bf16(accs[d2 * 81 + n]);
    }
}

// ---------------------------------------------------------------------------
// Stage D: per-head MFMA GEMM: attn[l, 0..79] = q_[l, 0..127] @ Bt^T
// 256 q-rows per block (Bt staged once per 2 q-tiles).
// grid (16, 64), 256 threads.
// ---------------------------------------------------------------------------
__global__ __launch_bounds__(256) void attn_mfma(const u16* __restrict__ qb,
                                                 const u16* __restrict__ Bt,
                                                 u16* __restrict__ merged) {
    __shared__ __align__(16) u16 As[128 * 72];
    __shared__ __align__(16) u16 Bs[80 * 136];
    const int tid = threadIdx.x;
    const int wave = tid >> 6, lane = tid & 63;
    const int quad = lane >> 4, l15 = lane & 15;
    const int head = blockIdx.y;
    const int b = head >> 4, h = head & 15;
    const int tm0 = blockIdx.x * 256;
    const long b4 = (long)b * 4096;
    const int wm = wave * 32;

    for (int c = tid; c < 1280; c += 256) {
        const int row = c >> 4, c16 = c & 15;
        uint4 t = *(const uint4*)(Bt + (long)head * 10240 + row * 128 + c16 * 8);
        *(uint4*)&Bs[row * 136 + c16 * 8] = t;
    }

#pragma unroll 1
    for (int half = 0; half < 2; ++half) {
        const int tm = tm0 + half * 128;
        __syncthreads();
        for (int c = tid; c < 1024; c += 256) {
            const int row = c >> 3, c8 = c & 7;
            uint4 t = *(const uint4*)(qb + (b4 + tm + row) * 1024 + h * 64 + c8 * 8);
            *(uint4*)&As[row * 72 + c8 * 8] = t;
        }
        float snl[2], csl[2];
#pragma unroll
        for (int i = 0; i < 2; i++) {
            const int l = tm + wm + i * 16 + l15;
            const float idx = PI_HALF * (float)(l + 1) * (1.0f / 4096.0f);
            snl[i] = sinf(idx); csl[i] = cosf(idx);
        }
        __syncthreads();

        f32x4 acc[2][5] = {};
#pragma unroll
        for (int kb = 0; kb < 4; kb++) {
            const int qc = (kb & 1) * 32 + quad * 8;
            bf16x8 af[2];
#pragma unroll
            for (int i = 0; i < 2; i++) {
                bf16x8 raw = *(const bf16x8*)&As[(wm + i * 16 + l15) * 72 + qc];
                const float s = (kb < 2) ? snl[i] : csl[i];
                bf16x8 sc;
#pragma unroll
                for (int e = 0; e < 8; e++) sc[e] = (__bf16)((float)raw[e] * s);
                af[i] = sc;
            }
            bf16x8 bf[5];
#pragma unroll
            for (int j = 0; j < 5; j++)
                bf[j] = *(const bf16x8*)&Bs[(j * 16 + l15) * 136 + kb * 32 + quad * 8];
#pragma unroll
            for (int i = 0; i < 2; i++)
#pragma unroll
                for (int j = 0; j < 5; j++)
                    acc[i][j] = __builtin_amdgcn_mfma_f32_16x16x32_bf16(
                        af[i], bf[j], acc[i][j], 0, 0, 0);
        }

        __syncthreads();
#pragma unroll
        for (int i = 0; i < 2; i++) {
            float z[4];
#pragma unroll
            for (int r = 0; r < 4; r++) {
                const float den = __shfl(acc[i][4][r], lane & 0x30, 64);
                z[r] = 1.0f / fmaxf(den, EPS_Z);
            }
#pragma unroll
            for (int j = 0; j < 4; j++)
#pragma unroll
                for (int r = 0; r < 4; r++) {
                    const int row = wm + i * 16 + quad * 4 + r;
                    As[row * 64 + j * 16 + l15] = f32_to_bf16(acc[i][j][r] * z[r]);
                }
        }
        __syncthreads();
        const int rloc = tid >> 3, c8o = (tid & 7) * 8;
#pragma unroll
        for (int it = 0; it < 4; ++it) {
            const int row = it * 32 + rloc;
            uint4 t4 = *(const uint4*)&As[row * 64 + c8o];
            *(uint4*)&merged[(b4 + tm + row) * 1024 + h * 64 + c8o] = t4;
        }
    }
}

// ---------------------------------------------------------------------------
extern "C" void kernel_launch(void* const* d_in, const int* in_sizes, int n_in,
                              void* d_out, int out_size, void* d_ws, size_t ws_size,
                              hipStream_t stream) {
    (void)in_sizes; (void)n_in; (void)out_size; (void)ws_size;
    const float* x  = (const float*)d_in[0];
    const float* Wq = (const float*)d_in[1];
    const float* bq = (const float*)d_in[2];
    const float* Wk = (const float*)d_in[3];
    const float* bk = (const float*)d_in[4];
    const float* Wv = (const float*)d_in[5];
    const float* bv = (const float*)d_in[6];
    const float* Wo = (const float*)d_in[7];
    const float* bo = (const float*)d_in[8];
    float* out = (float*)d_out;

    const int E = 1024;
    char* ws = (char*)d_ws;
    const size_t MB = 1048576;
    u16* xb   = (u16*)(ws);              // 32 MiB; dead after QKV GEMM -> part
    u16* qb   = (u16*)(ws + 32 * MB);
    u16* kb   = (u16*)(ws + 64 * MB);    // dead after kv_mfma -> merged
    u16* vb   = (u16*)(ws + 96 * MB);
    u16* wcat = (u16*)(ws + 128 * MB);   // Wq;Wk;Wv;Wo bf16, 8 MiB
    u16* wob  = wcat + 3 * (size_t)E * E;
    u16* Btb  = (u16*)(ws + 136 * MB);   // 1.25 MiB
    float* part = (float*)xb;            // 8*64*10240*4 = 20 MiB
    u16* mergedb = kb;

    cvt_all<<<dim3(2048), dim3(256), 0, stream>>>(x, Wq, Wk, Wv, Wo, xb, wcat);

    gemm_qkv<<<dim3(768), dim3(512), 0, stream>>>(xb, wcat, bq, bk, bv, qb, kb, vb);

    kv_mfma<<<dim3(8, 64), dim3(256), 0, stream>>>(kb, vb, part);
    kv_reduce_t<<<dim3(4, 64), dim3(256), 0, stream>>>(part, Btb);
    attn_mfma<<<dim3(16, 64), dim3(256), 0, stream>>>(qb, Btb, mergedb);

    gemm_o<<<dim3(256), dim3(512), 0, stream>>>(mergedb, wob, bo, out);
}